// Round 1
// 852.879 us; speedup vs baseline: 1.0811x; 1.0811x over previous
//
#include <hip/hip_runtime.h>
#include <hip/hip_bf16.h>

// B=8, C=512, G=32, HW=4096. All matrix dims are multiples of 128 -> no guards.
typedef __attribute__((ext_vector_type(8))) short short8;
typedef __attribute__((ext_vector_type(4))) float f32x4;

#define ALPHA 0.044194173824159216f

__device__ __forceinline__ unsigned short f2bf(float f) {
    union { float f; unsigned int u; } c; c.f = f;
    unsigned int u = c.u;
    return (unsigned short)((u + 0x7FFFu + ((u >> 16) & 1u)) >> 16);
}

// ---------------- GroupNorm stats: one block per (b,g), 16ch x 4096 contiguous ----
__global__ __launch_bounds__(256) void gn_stats(const float* __restrict__ x,
                                                float* __restrict__ stats) {
    int blk = blockIdx.x;  // b*32 + g
    const float4* src = (const float4*)(x + (size_t)blk * 65536);
    float s = 0.f, sq = 0.f;
    for (int i = threadIdx.x; i < 16384; i += 256) {
        float4 v = src[i];
        s  += v.x + v.y + v.z + v.w;
        sq += v.x*v.x + v.y*v.y + v.z*v.z + v.w*v.w;
    }
    for (int off = 32; off; off >>= 1) {
        s  += __shfl_down(s, off);
        sq += __shfl_down(sq, off);
    }
    __shared__ float ss[4], ssq[4];
    int wid = threadIdx.x >> 6;
    if ((threadIdx.x & 63) == 0) { ss[wid] = s; ssq[wid] = sq; }
    __syncthreads();
    if (threadIdx.x == 0) {
        float S = ss[0]+ss[1]+ss[2]+ss[3], Q = ssq[0]+ssq[1]+ssq[2]+ssq[3];
        float mu = S * (1.f/65536.f);
        float var = Q * (1.f/65536.f) - mu*mu;
        stats[blk] = mu;
        stats[256 + blk] = rsqrtf(var + 1e-6f);
    }
}

// ---------------- weight fp32 -> bf16 ----------------
__global__ __launch_bounds__(256) void wcvt(const float* __restrict__ s,
                                            unsigned short* __restrict__ d) {
    int i = blockIdx.x * 1024 + threadIdx.x * 4;
    float4 v = *(const float4*)(s + i);
    ushort4 o = make_ushort4(f2bf(v.x), f2bf(v.y), f2bf(v.z), f2bf(v.w));
    *(ushort4*)(d + i) = o;
}

// ---------------- zero the softmax-denominator accumulator ----------------
__global__ __launch_bounds__(256) void zero_l(float* __restrict__ l) {
    ((float4*)l)[blockIdx.x * 256 + threadIdx.x] = make_float4(0.f, 0.f, 0.f, 0.f);
}

// ------- GN apply + transpose: x[b][c][hw] fp32 -> h[(b*4096+hw)][c] bf16 -------
__global__ __launch_bounds__(256) void gn_apply(const float* __restrict__ x,
                                                const float* __restrict__ stats,
                                                const float* __restrict__ gamma,
                                                const float* __restrict__ beta,
                                                unsigned short* __restrict__ h) {
    __shared__ unsigned short t[64][72];  // [hw_local][c_local], pad 72
    int b = blockIdx.z, c0 = blockIdx.y * 64, hw0 = blockIdx.x * 64;
    int tid = threadIdx.x;
#pragma unroll
    for (int rep = 0; rep < 4; ++rep) {
        int lin = rep * 256 + tid;         // 1024 = 64 c-rows x 16 float4
        int row = lin >> 4;                // c_local
        int c4  = lin & 15;                // float4 idx along hw
        int c   = c0 + row;
        const float4* src = (const float4*)(x + ((size_t)(b*512 + c) << 12) + hw0);
        float4 v = src[c4];
        int sidx = b*32 + (c >> 4);
        float mu = stats[sidx], rs = stats[256 + sidx];
        float ga = gamma[c] * rs, be = beta[c] - mu * ga;
        t[c4*4+0][row] = f2bf(v.x * ga + be);
        t[c4*4+1][row] = f2bf(v.y * ga + be);
        t[c4*4+2][row] = f2bf(v.z * ga + be);
        t[c4*4+3][row] = f2bf(v.w * ga + be);
    }
    __syncthreads();
#pragma unroll
    for (int rep = 0; rep < 2; ++rep) {
        int lin = rep * 256 + tid;         // 512 = 64 hw-rows x 8 groups
        int row = lin >> 3;                // hw_local
        int u8  = lin & 7;
        unsigned short* dst = h + (((size_t)(b*4096 + hw0 + row)) << 9) + c0 + u8*8;
        *(short8*)dst = *(const short8*)&t[row][u8*8];
    }
}

// ---------------- universal 128x128 bf16 MFMA GEMM, BK=64 ----------------
// C[m,n] = sum_k A[m,k] * B[n,k]
// mode 0: out bf16, out[m*ldo+n] = bf16((acc + bias[n]) * scale)          (q/k proj)
// mode 1: out bf16, out[m*ldo+n] = bf16(acc + bias[m])                    (vT proj)
// mode 2: out fp32 d_out[b][m][hw], n = b*4096+hw:
//           acc/lvec[n] + bias[m] + resid                                 (o-proj)
// mode 3: out bf16 P[m*ldo+n] = bf16(exp(acc)); atomicAdd row sums to lout (S pass)
__global__ __launch_bounds__(256, 2) void gemm_bt(const unsigned short* __restrict__ A,
                                                  int lda, long aZs,
                                                  const unsigned short* __restrict__ B,
                                                  int ldb, long bZs,
                                                  const float* __restrict__ bias,
                                                  const float* __restrict__ resid,
                                                  const float* __restrict__ lvec,
                                                  float* __restrict__ lout,
                                                  void* __restrict__ out,
                                                  long ldo, long oZs,
                                                  int K, int mode, float scale) {
    __shared__ unsigned short As[128][72], Bs[128][72];  // 64-wide K-slab, pad 72
    int z = blockIdx.z;
    A += (size_t)z * aZs;
    B += (size_t)z * bZs;
    unsigned short* outu = (unsigned short*)out + (size_t)z * oZs;
    if (lout) lout += (size_t)z * 4096;
    int m0 = blockIdx.y * 128, n0 = blockIdx.x * 128;
    int tid = threadIdx.x, w = tid >> 6, l = tid & 63;
    int lr = l & 15, lq = l >> 4, lk = lq * 8;
    int rbase = (w >> 1) * 64, cbase = (w & 1) * 64;
    f32x4 acc[4][4] = {};
    for (int k0 = 0; k0 < K; k0 += 64) {
        __syncthreads();
#pragma unroll
        for (int p = 0; p < 4; ++p) {
            int lin = p * 256 + tid;           // 1024 = 128 rows x 8 short8
            int r = lin >> 3, qq = lin & 7;
            *(short8*)&As[r][qq*8] = *(const short8*)(A + (size_t)(m0 + r)*lda + k0 + qq*8);
            *(short8*)&Bs[r][qq*8] = *(const short8*)(B + (size_t)(n0 + r)*ldb + k0 + qq*8);
        }
        __syncthreads();
        short8 af[4][2], bfv[4][2];
#pragma unroll
        for (int i = 0; i < 4; ++i)
#pragma unroll
            for (int ks = 0; ks < 2; ++ks) {
                af[i][ks]  = *(const short8*)&As[rbase + i*16 + lr][ks*32 + lk];
                bfv[i][ks] = *(const short8*)&Bs[cbase + i*16 + lr][ks*32 + lk];
            }
#pragma unroll
        for (int ks = 0; ks < 2; ++ks)
#pragma unroll
            for (int i = 0; i < 4; ++i)
#pragma unroll
                for (int j = 0; j < 4; ++j)
                    acc[i][j] = __builtin_amdgcn_mfma_f32_16x16x32_bf16(af[i][ks], bfv[j][ks], acc[i][j], 0, 0, 0);
    }
    // epilogue: C row = 4*lq + r (within 16-tile), col = lr
    int lq4 = lq * 4;
    if (mode == 3) {
#pragma unroll
        for (int i = 0; i < 4; ++i) {
            int rowl = rbase + i*16 + lq4;
#pragma unroll
            for (int r = 0; r < 4; ++r) {
                float s = 0.f;
#pragma unroll
                for (int j = 0; j < 4; ++j) {
                    float e = __expf(acc[i][j][r]);
                    s += e;
                    outu[(size_t)(m0 + rowl + r) * ldo + n0 + cbase + j*16 + lr] = f2bf(e);
                }
                s += __shfl_xor(s, 1); s += __shfl_xor(s, 2);
                s += __shfl_xor(s, 4); s += __shfl_xor(s, 8);
                if (lr == 0) atomicAdd(&lout[m0 + rowl + r], s);
            }
        }
        return;
    }
#pragma unroll
    for (int i = 0; i < 4; ++i) {
        int rowg = m0 + rbase + i*16 + lq4;
#pragma unroll
        for (int j = 0; j < 4; ++j) {
            int colg = n0 + cbase + j*16 + lr;
#pragma unroll
            for (int r = 0; r < 4; ++r) {
                float v = acc[i][j][r];
                int rr = rowg + r;
                if (mode == 0) {
                    outu[(size_t)rr * ldo + colg] = f2bf((v + bias[colg]) * scale);
                } else if (mode == 1) {
                    outu[(size_t)rr * ldo + colg] = f2bf(v + bias[rr]);
                } else {
                    size_t addr = ((size_t)(colg >> 12)) * 2097152 + (size_t)rr * 4096 + (colg & 4095);
                    ((float*)out)[addr] = v / lvec[colg] + bias[rr] + resid[addr];
                }
            }
        }
    }
}

// ---------------- P*V pass: 128x128 tiles (gemm_bt body), XCD-swizzled ----------------
// o_unnorm[(zofs+z)*4096 + m][n] = sum_k P[z][m][k] * vt[n][(zofs+z)*4096 + k]
// P batches 0,1 at P0 (+z*16M), batches 2,3 at P1 (+(z-2)*16M).
// 1-D grid of nwg blocks (nwg % 8 == 0). Bijective XCD swizzle gives each XCD a
// contiguous chunk of work; the 4 consecutive n-blocks sharing a P row-block land
// on one XCD's L2 (P row-block fetched ~once per XCD instead of 4x from HBM).
__global__ __launch_bounds__(256, 2) void gemm_pv(const unsigned short* __restrict__ P0,
                                                  const unsigned short* __restrict__ P1,
                                                  const unsigned short* __restrict__ vt,
                                                  unsigned short* __restrict__ o,
                                                  int zofs, int nwg) {
    __shared__ unsigned short As[128][72], Bs[128][72];
    int h = blockIdx.x;
    int qc = nwg >> 3;
    int wk = (h & 7) * qc + (h >> 3);   // bijective: nwg % 8 == 0
    int z = wk >> 7;                    // 128 work items per batch (32 m x 4 n)
    int rem = wk & 127;
    int m0 = (rem >> 2) * 128, n0 = (rem & 3) * 128;
    const unsigned short* A = (z < 2) ? P0 + (size_t)z * 16777216
                                      : P1 + (size_t)(z - 2) * 16777216;
    int zb = zofs + z;
    const unsigned short* vb = vt + (size_t)zb * 4096;
    int tid = threadIdx.x, w = tid >> 6, l = tid & 63;
    int lr = l & 15, lq = l >> 4, lk = lq * 8;
    int rbase = (w >> 1) * 64, cbase = (w & 1) * 64;
    f32x4 acc[4][4] = {};
    for (int k0 = 0; k0 < 4096; k0 += 64) {
        __syncthreads();
#pragma unroll
        for (int p = 0; p < 4; ++p) {
            int lin = p * 256 + tid;            // 1024 = 128 rows x 8 short8
            int r = lin >> 3, qq = lin & 7;
            *(short8*)&As[r][qq*8] = *(const short8*)(A + (size_t)(m0 + r)*4096 + k0 + qq*8);
            *(short8*)&Bs[r][qq*8] = *(const short8*)(vb + (size_t)(n0 + r)*32768 + k0 + qq*8);
        }
        __syncthreads();
        short8 af[4][2], bfv[4][2];
#pragma unroll
        for (int i = 0; i < 4; ++i)
#pragma unroll
            for (int ks = 0; ks < 2; ++ks) {
                af[i][ks]  = *(const short8*)&As[rbase + i*16 + lr][ks*32 + lk];
                bfv[i][ks] = *(const short8*)&Bs[cbase + i*16 + lr][ks*32 + lk];
            }
#pragma unroll
        for (int ks = 0; ks < 2; ++ks)
#pragma unroll
            for (int i = 0; i < 4; ++i)
#pragma unroll
                for (int j = 0; j < 4; ++j)
                    acc[i][j] = __builtin_amdgcn_mfma_f32_16x16x32_bf16(af[i][ks], bfv[j][ks], acc[i][j], 0, 0, 0);
    }
    unsigned short* ob = o + ((size_t)zb * 4096 + m0) * 512 + n0;
    int lq4 = lq * 4;
#pragma unroll
    for (int i = 0; i < 4; ++i)
#pragma unroll
        for (int j = 0; j < 4; ++j)
#pragma unroll
            for (int r = 0; r < 4; ++r)
                ob[(size_t)(rbase + i*16 + lq4 + r) * 512 + cbase + j*16 + lr] = f2bf(acc[i][j][r]);
}

extern "C" void kernel_launch(void* const* d_in, const int* in_sizes, int n_in,
                              void* d_out, int out_size, void* d_ws, size_t ws_size,
                              hipStream_t stream) {
    const float* x     = (const float*)d_in[0];
    const float* gamma = (const float*)d_in[1];
    const float* beta  = (const float*)d_in[2];
    const float* wq = (const float*)d_in[3];  const float* bq = (const float*)d_in[4];
    const float* wk = (const float*)d_in[5];  const float* bk = (const float*)d_in[6];
    const float* wv = (const float*)d_in[7];  const float* bv = (const float*)d_in[8];
    const float* wo = (const float*)d_in[9];  const float* bo = (const float*)d_in[10];

    // ---- base workspace layout (proven, ends at 136,448,000 B) ----
    char* wsp = (char*)d_ws;
    float* stats        = (float*)wsp;                    //   2 KB
    unsigned short* wqb = (unsigned short*)(wsp + 2048);  // 512 KB each
    unsigned short* wkb = wqb + 262144;
    unsigned short* wvb = wkb + 262144;
    unsigned short* wob = wvb + 262144;
    unsigned short* h   = wob + 262144;                   // 32 MB [B*HW, C] bf16
    unsigned short* qb  = h  + 16777216;                  // 32 MB
    unsigned short* kb  = qb + 16777216;                  // 32 MB
    unsigned short* vtb = kb + 16777216;                  // 32 MB [C, B*HW] bf16
    float* lbuf         = (float*)(vtb + 16777216);       // 128 KB softmax denoms
    unsigned short* Pw  = (unsigned short*)(lbuf + 32768);// mid path: +64 MB, ends 203.6 MB
    unsigned short* Pd  = (unsigned short*)d_out;         // 64 MB: 2 batches of P
    unsigned short* ob  = h;                              // alias: h dead after vT GEMM

    // mid path needs 203,556,864 B total
    const bool mid = ws_size >= 204000000ull;

    gn_stats<<<256, 256, 0, stream>>>(x, stats);
    wcvt<<<256, 256, 0, stream>>>(wq, wqb);
    wcvt<<<256, 256, 0, stream>>>(wk, wkb);
    wcvt<<<256, 256, 0, stream>>>(wv, wvb);
    wcvt<<<256, 256, 0, stream>>>(wo, wob);
    gn_apply<<<dim3(64, 8, 8), 256, 0, stream>>>(x, stats, gamma, beta, h);
    zero_l<<<32, 256, 0, stream>>>(lbuf);

    // q = alpha*(h wq^T + bq), k = h wk^T + bk  : [32768 x 512]
    gemm_bt<<<dim3(4, 256), 256, 0, stream>>>(h, 512, 0, wqb, 512, 0, bq, nullptr, nullptr, nullptr,
                                              qb, 512, 0, 512, 0, ALPHA);
    gemm_bt<<<dim3(4, 256), 256, 0, stream>>>(h, 512, 0, wkb, 512, 0, bk, nullptr, nullptr, nullptr,
                                              kb, 512, 0, 512, 0, 1.0f);
    // vT[c, pos] = wv h^T + bv : [512 x 32768]
    gemm_bt<<<dim3(256, 4), 256, 0, stream>>>(wvb, 512, 0, h, 512, 0, bv, nullptr, nullptr, nullptr,
                                              vtb, 32768, 0, 512, 1, 1.0f);

    const long QS = (long)4096 * 512;   // per-batch q/k/o stride
    const long PS = (long)4096 * 4096;  // per-batch P stride
    if (mid) {
        // ---- 2 chunks x 4 batches: P in d_out (2) + ws tail (2); PV at 512 blocks ----
        for (int c = 0; c < 2; ++c) {
            size_t z0 = (size_t)c * 4;
            gemm_bt<<<dim3(32, 32, 2), 256, 0, stream>>>(
                qb + z0 * QS, 512, QS, kb + z0 * QS, 512, QS,
                nullptr, nullptr, nullptr, lbuf + z0 * 4096,
                Pd, 4096, PS, 512, 3, 1.0f);
            gemm_bt<<<dim3(32, 32, 2), 256, 0, stream>>>(
                qb + (z0 + 2) * QS, 512, QS, kb + (z0 + 2) * QS, 512, QS,
                nullptr, nullptr, nullptr, lbuf + (z0 + 2) * 4096,
                Pw, 4096, PS, 512, 3, 1.0f);
            gemm_pv<<<512, 256, 0, stream>>>(Pd, Pw, vtb, ob, (int)z0, 512);
        }
    } else {
        // ---- 4 chunks x 2 batches: P in d_out only; PV at 256 blocks ----
        for (int c = 0; c < 4; ++c) {
            size_t z0 = (size_t)c * 2;
            gemm_bt<<<dim3(32, 32, 2), 256, 0, stream>>>(
                qb + z0 * QS, 512, QS, kb + z0 * QS, 512, QS,
                nullptr, nullptr, nullptr, lbuf + z0 * 4096,
                Pd, 4096, PS, 512, 3, 1.0f);
            gemm_pv<<<256, 256, 0, stream>>>(Pd, Pd, vtb, ob, (int)z0, 256);
        }
    }
    // out[b,c,hw] = (wo o_unnorm^T)/l + bo + x   (overwrites all of d_out)
    gemm_bt<<<dim3(256, 4), 256, 0, stream>>>(wob, 512, 0, ob, 512, 0, bo, x, lbuf, nullptr,
                                              d_out, 0, 0, 512, 2, 1.0f);
}